// Round 7
// baseline (405.351 us; speedup 1.0000x reference)
//
#include <hip/hip_runtime.h>
#include <hip/hip_bf16.h>

#define B_ 32
#define S_ 2048
#define D_ 1024

// 128x128 tile, BK=64, 4 waves, 64 KiB LDS -> 2 blocks/CU
#define BM 128
#define BN 128
#define BK 64
#define NKT (D_ / BK)   // 16 K-tiles

typedef __attribute__((ext_vector_type(8))) short bf16x8;
typedef __attribute__((ext_vector_type(4))) float f32x4;
typedef __attribute__((ext_vector_type(4))) float float4v;

#define AS1 __attribute__((address_space(1)))
#define AS3 __attribute__((address_space(3)))

// f32 -> bf16 round-to-nearest-even on raw bits
__device__ __forceinline__ short f2bf(float f) {
    union { float f; unsigned u; } uf;
    uf.f = f;
    unsigned u = uf.u;
    u += 0x7FFFu + ((u >> 16) & 1u);
    return (short)(u >> 16);
}

// ---------------- pre-convert: f32 -> bf16, 8 floats/thread ----------------
__global__ __launch_bounds__(256) void cvt_bf16(const float4v* __restrict__ src,
                                                bf16x8* __restrict__ dst, int n8) {
    const int stride = gridDim.x * blockDim.x;
    for (int i = blockIdx.x * blockDim.x + threadIdx.x; i < n8; i += stride) {
        float4v a = src[2 * i], b = src[2 * i + 1];
        bf16x8 v;
#pragma unroll
        for (int j = 0; j < 4; ++j) {
            v[j]     = f2bf(a[j]);
            v[4 + j] = f2bf(b[j]);
        }
        dst[i] = v;
    }
}

// ============================================================================
// GEMM: both operands bf16, staged entirely via global_load_lds (width 16).
// LDS halves: half h of a 128-row operand tile holds global rows with bit5==h,
//   lds row (h*64 + l) <-> global row (l>>5)*64 + h*32 + (l&31).
// Byte swizzle within a 128B row: stored byte = logical byte ^ ((row&7)<<4),
// applied via pre-swizzled GLOBAL source (linear LDS dest) + swizzled read.
// Phase p=(mh,bh) reads exactly A-half mh and B-half bh -> per-phase counted
// vmcnt(6) retires exactly the half the phase needs (stage order A0,B0,B1,A1).
// ============================================================================

// ---- stage one half (2 x global_load_lds, 64 rows x 128B = 8 KB) ----
#define STG(arr, nb, gbase, h, kt) do {                                        \
    _Pragma("unroll")                                                          \
    for (int _j = 0; _j < 2; ++_j) {                                           \
        const int _lr = (h) * 64 + _j * 32 + wid * 8 + lrow8;                  \
        const int _gr = _j * 64 + (h) * 32 + wid * 8 + lrow8;                  \
        const __hip_bfloat16* _g = (gbase) + (size_t)_gr * D_ + (kt) * BK + (scb >> 1); \
        __builtin_amdgcn_global_load_lds((const AS1 unsigned int*)_g,          \
            (AS3 unsigned int*)&arr[nb][_lr * 64 + (lane & 7) * 8], 16, 0, 0); \
    } } while (0)

// ---- one quadrant: A-half mh x B-half bh, 8 MFMA, 8 ds_read_b128 ----
#define COMPUTE(cur, mh, bh) do {                                              \
    bf16x8 _af[2][2], _bv[2][2];                                               \
    _Pragma("unroll")                                                          \
    for (int _mi = 0; _mi < 2; ++_mi) {                                        \
        const int _l = (mh) * 64 + wm * 32 + _mi * 16 + fr;                    \
        _Pragma("unroll")                                                      \
        for (int _kk = 0; _kk < 2; ++_kk) {                                    \
            const int _b = _l * 128 + ((_kk * 64 + fg * 16) ^ ((_l & 7) << 4)); \
            _af[_mi][_kk] = *(const bf16x8*)((const char*)&As[cur][0] + _b);   \
        }                                                                      \
    }                                                                          \
    _Pragma("unroll")                                                          \
    for (int _ni = 0; _ni < 2; ++_ni) {                                        \
        const int _l = (bh) * 64 + wn * 32 + _ni * 16 + fr;                    \
        _Pragma("unroll")                                                      \
        for (int _kk = 0; _kk < 2; ++_kk) {                                    \
            const int _b = _l * 128 + ((_kk * 64 + fg * 16) ^ ((_l & 7) << 4)); \
            _bv[_ni][_kk] = *(const bf16x8*)((const char*)&Bs[cur][0] + _b);   \
        }                                                                      \
    }                                                                          \
    __builtin_amdgcn_s_setprio(1);                                             \
    _Pragma("unroll")                                                          \
    for (int _mi = 0; _mi < 2; ++_mi)                                          \
        _Pragma("unroll")                                                      \
        for (int _ni = 0; _ni < 2; ++_ni)                                      \
            _Pragma("unroll")                                                  \
            for (int _kk = 0; _kk < 2; ++_kk)                                  \
                acc[(mh) * 2 + _mi][(bh) * 2 + _ni] =                          \
                    __builtin_amdgcn_mfma_f32_16x16x32_bf16(                   \
                        _af[_mi][_kk], _bv[_ni][_kk],                          \
                        acc[(mh) * 2 + _mi][(bh) * 2 + _ni], 0, 0, 0);         \
    __builtin_amdgcn_s_setprio(0); } while (0)

#define VMW(n)  asm volatile("s_waitcnt vmcnt(" #n ")" ::: "memory")
#define SBAR()  asm volatile("s_barrier" ::: "memory")

// Compute tile on buf X; stage tile kn into buf Y (order A0,B0,B1,A1).
// Steady state: 4 half-groups (8 loads) in flight; each vmcnt(6) retires
// exactly the half this phase needs (FIFO-verified, incl. first iteration).
#define KITER(X, Y, kn) do {                                                   \
    STG(As, Y, aBase, 0, kn); VMW(6); SBAR(); COMPUTE(X, 0, 0);                \
    STG(Bs, Y, bBase, 0, kn); VMW(6); SBAR(); COMPUTE(X, 0, 1);                \
    STG(Bs, Y, bBase, 1, kn); VMW(6); SBAR(); COMPUTE(X, 1, 0);                \
    STG(As, Y, aBase, 1, kn); VMW(6); SBAR(); COMPUTE(X, 1, 1);                \
} while (0)

// Final tile: no staging; drain the remaining halves (B0,B1,A1) as needed.
#define KITER_LAST(X) do {                                                     \
    VMW(4); SBAR(); COMPUTE(X, 0, 0);                                          \
    VMW(2); SBAR(); COMPUTE(X, 0, 1);                                          \
    VMW(0); SBAR(); COMPUTE(X, 1, 0);                                          \
            SBAR(); COMPUTE(X, 1, 1);                                          \
} while (0)

__global__ __launch_bounds__(256, 2) void fused_gemm_bf16(
    const __hip_bfloat16* __restrict__ aBf,   // [B][S][D] bf16 (pre-converted)
    const __hip_bfloat16* __restrict__ wBf,   // [3][D][D] bf16 (pre-converted)
    const int*   __restrict__ scale_id,
    const int*   __restrict__ mask,
    const float* __restrict__ bias,
    const float* __restrict__ scemb,
    const float* __restrict__ bremb,
    float*       __restrict__ out,
    float*       __restrict__ colws)
{
    __shared__ __align__(16) short As[2][BM * BK];   // 2 x 16 KB
    __shared__ __align__(16) short Bs[2][BM * BK];   // 2 x 16 KB (total 64 KB)

    const int tid = threadIdx.x;
    const int lane = tid & 63;
    const int wid = tid >> 6;                 // 0..3
    const int wm = wid >> 1, wn = wid & 1;    // 2x2 waves, 64x64 each

    // chunked XCD swizzle (NWG = 4096)
    const int NTI = D_ / BN;  // 8
    const int MTI = S_ / BM;  // 16
    const int NWG = B_ * MTI * NTI;
    const int CPX = NWG / 8;
    int lid = ((int)blockIdx.x % 8) * CPX + ((int)blockIdx.x / 8);
    int nt = lid % NTI;
    int mt = (lid / NTI) % MTI;
    int bb = lid / (NTI * MTI);

    const int sid = scale_id[bb];
    const __hip_bfloat16* aBase = aBf + ((size_t)bb * S_ + (size_t)mt * BM) * D_;
    const __hip_bfloat16* bBase = wBf + ((size_t)sid * D_ + (size_t)nt * BN) * D_;

    // staging lane geometry: per issue, 256 threads cover 32 rows x 128B
    const int lrow8 = lane >> 3;                         // 0..7
    const int scb = ((lane & 7) * 16) ^ (lrow8 << 4);    // pre-swizzled col byte

    const int fr = lane & 15;
    const int fg = lane >> 4;

    f32x4 acc[4][4];
#pragma unroll
    for (int mi = 0; mi < 4; ++mi)
#pragma unroll
        for (int ni = 0; ni < 4; ++ni)
            acc[mi][ni] = (f32x4){0.f, 0.f, 0.f, 0.f};

    // prologue: tile 0 into buf 0, steady-state FIFO order A0,B0,B1,A1
    STG(As, 0, aBase, 0, 0);
    STG(Bs, 0, bBase, 0, 0);
    STG(Bs, 0, bBase, 1, 0);
    STG(As, 0, aBase, 1, 0);

    // tiles 0..13 (7 pairs), each stages the next tile
#pragma unroll 1
    for (int kt = 0; kt < NKT - 2; kt += 2) {
        KITER(0, 1, kt + 1);
        KITER(1, 0, kt + 2);
    }
    KITER(0, 1, NKT - 1);   // tile 14, stages tile 15 -> buf1
    KITER_LAST(1);          // tile 15, no staging, drains vmcnt to 0

    __syncthreads();        // all loads drained; LDS reusable

    // ---- epilogue phase 1: silu + scale_embed in-register, masked colsums ----
    // acc[mig][nig]: row = wm*64 + (mig>>1)*32 + (mig&1)*16 + fg*4 + r
    //                col = wn*64 + (nig>>1)*32 + (nig&1)*16 + fr
    const int colb = nt * BN;
    float bv[4], sv[4];
#pragma unroll
    for (int nig = 0; nig < 4; ++nig) {
        const int n = colb + wn * 64 + (nig >> 1) * 32 + (nig & 1) * 16 + fr;
        bv[nig] = bias[sid * D_ + n];
        sv[nig] = scemb[sid * D_ + n];
    }

    float colsum[4] = {0.f, 0.f, 0.f, 0.f};
#pragma unroll
    for (int mig = 0; mig < 4; ++mig) {
        const int mrow0 = mt * BM + wm * 64 + (mig >> 1) * 32 + (mig & 1) * 16 + fg * 4;
        float mk[4];
#pragma unroll
        for (int r = 0; r < 4; ++r)
            mk[r] = (mask[(size_t)bb * S_ + mrow0 + r] > 0) ? 1.f : 0.f;
#pragma unroll
        for (int nig = 0; nig < 4; ++nig)
#pragma unroll
            for (int r = 0; r < 4; ++r) {
                const float v = acc[mig][nig][r] + bv[nig];
                const float o = v / (1.f + __expf(-v)) + sv[nig];  // silu + scale_embed
                acc[mig][nig][r] = o;
                colsum[nig] += mk[r] * o;
            }
    }

#pragma unroll
    for (int nig = 0; nig < 4; ++nig) {
        float s = colsum[nig];
        s += __shfl_xor(s, 16);
        s += __shfl_xor(s, 32);
        if (fg == 0) {
            const int n = colb + wn * 64 + (nig >> 1) * 32 + (nig & 1) * 16 + fr;
            atomicAdd(&colws[(size_t)bb * D_ + n], s);
        }
    }

    // ---- epilogue phase 2: LDS bounce -> full-row contiguous float4 stores ----
    // ldsF[32][132] f32 = 16.9 KB in As. Per store instr: wave writes 2 rows x
    // 512B contiguous.
    float* ldsF = (float*)&As[0][0];
    const float4v b0 = *(const float4v*)&bremb[0 * D_ + colb + (lane & 31) * 4];
    const float4v b1 = *(const float4v*)&bremb[1 * D_ + colb + (lane & 31) * 4];
    const size_t MIDOFF = (size_t)B_ * S_ * D_;

#pragma unroll
    for (int mig = 0; mig < 4; ++mig) {
#pragma unroll
        for (int nig = 0; nig < 4; ++nig)
#pragma unroll
            for (int r = 0; r < 4; ++r)
                ldsF[(wm * 16 + fg * 4 + r) * 132 +
                     wn * 64 + (nig >> 1) * 32 + (nig & 1) * 16 + fr] =
                    acc[mig][nig][r];
        __syncthreads();

#pragma unroll
        for (int k = 0; k < 4; ++k) {
            const int lr = wid * 8 + k * 2 + (lane >> 5);   // 0..31
            const int grow = mt * BM + (lr >> 4) * 64 + (mig >> 1) * 32 +
                             (mig & 1) * 16 + (lr & 15);
            const size_t rowbase = ((size_t)bb * S_ + grow) * D_ + colb;
            float4v v = *(const float4v*)&ldsF[lr * 132 + (lane & 31) * 4];
            __builtin_nontemporal_store(v + b0, (float4v*)&out[rowbase + (lane & 31) * 4]);
            __builtin_nontemporal_store(v + b1, (float4v*)&out[MIDOFF + rowbase + (lane & 31) * 4]);
        }
        __syncthreads();
    }
}

// ---------------- fallback path (f32 reg-staging, 2-barrier) ---------------
__global__ __launch_bounds__(256, 2) void fused_gemm_f32(
    const float* __restrict__ midi,
    const int*   __restrict__ scale_id,
    const int*   __restrict__ mask,
    const float* __restrict__ W,
    const float* __restrict__ bias,
    const float* __restrict__ scemb,
    const float* __restrict__ bremb,
    float*       __restrict__ out,
    float*       __restrict__ ws)
{
    __shared__ __align__(16) short Asf[BM * BK];
    __shared__ __align__(16) short Bsf[BM * BK];

    const int tid = threadIdx.x;
    const int NTI = D_ / BN;
    const int MTI = S_ / BM;
    const int NWG = B_ * MTI * NTI;
    const int CPX = NWG / 8;
    int lid = ((int)blockIdx.x % 8) * CPX + ((int)blockIdx.x / 8);
    int nt = lid % NTI;
    int mt = (lid / NTI) % MTI;
    int bb = lid / (NTI * MTI);

    const int sid = scale_id[bb];
    const float* aBase = midi + ((size_t)bb * S_ + (size_t)mt * BM) * D_;
    const float* bBase = W + ((size_t)sid * D_ + (size_t)nt * BN) * D_;

    const int r0 = tid >> 3;
    const int kp = (tid & 7) * 8;

    float4v aL[4], aH[4], bL[4], bH[4];

    auto load_regs = [&](int kt) {
        const int kc = kt * BK + kp;
#pragma unroll
        for (int i = 0; i < 4; ++i) {
            const float* pa = aBase + (size_t)(r0 + 32 * i) * D_ + kc;
            aL[i] = *(const float4v*)pa;
            aH[i] = *(const float4v*)(pa + 4);
            const float* pb = bBase + (size_t)(r0 + 32 * i) * D_ + kc;
            bL[i] = *(const float4v*)pb;
            bH[i] = *(const float4v*)(pb + 4);
        }
    };

    auto write_lds = [&]() {
#pragma unroll
        for (int i = 0; i < 4; ++i) {
            const int row = r0 + 32 * i;
            const int off = (row * BK + kp) ^ ((row & 7) << 3);
            bf16x8 va, vb;
#pragma unroll
            for (int j = 0; j < 4; ++j) {
                va[j]     = f2bf(aL[i][j]);
                va[4 + j] = f2bf(aH[i][j]);
                vb[j]     = f2bf(bL[i][j]);
                vb[4 + j] = f2bf(bH[i][j]);
            }
            *(bf16x8*)&Asf[off] = va;
            *(bf16x8*)&Bsf[off] = vb;
        }
    };

    f32x4 acc[4][4];
#pragma unroll
    for (int mi = 0; mi < 4; ++mi)
#pragma unroll
        for (int ni = 0; ni < 4; ++ni)
            acc[mi][ni] = (f32x4){0.f, 0.f, 0.f, 0.f};

    const int lane = tid & 63;
    const int wid = tid >> 6;
    const int wm = wid >> 1, wn = wid & 1;
    const int fr = lane & 15;
    const int fg = lane >> 4;

    load_regs(0);
    write_lds();
    __syncthreads();

    for (int kt = 0; kt < NKT; ++kt) {
        if (kt + 1 < NKT) load_regs(kt + 1);
#pragma unroll
        for (int kk = 0; kk < 2; ++kk) {
            bf16x8 af[4], bfr[4];
#pragma unroll
            for (int mi = 0; mi < 4; ++mi) {
                const int row = wm * 64 + mi * 16 + fr;
                const int off = (row * BK + kk * 32 + fg * 8) ^ ((row & 7) << 3);
                af[mi] = *(const bf16x8*)&Asf[off];
            }
#pragma unroll
            for (int ni = 0; ni < 4; ++ni) {
                const int row = wn * 64 + ni * 16 + fr;
                const int off = (row * BK + kk * 32 + fg * 8) ^ ((row & 7) << 3);
                bfr[ni] = *(const bf16x8*)&Bsf[off];
            }
#pragma unroll
            for (int mi = 0; mi < 4; ++mi)
#pragma unroll
                for (int ni = 0; ni < 4; ++ni)
                    acc[mi][ni] = __builtin_amdgcn_mfma_f32_16x16x32_bf16(
                        af[mi], bfr[ni], acc[mi][ni], 0, 0, 0);
        }
        __syncthreads();
        if (kt + 1 < NKT) write_lds();
        __syncthreads();
    }

    const int ncolbase = nt * BN + wn * 64;
    float bv[4], sv[4], b0v[4], b1v[4];
#pragma unroll
    for (int ni = 0; ni < 4; ++ni) {
        const int n = ncolbase + ni * 16 + fr;
        bv[ni]  = bias[sid * D_ + n];
        sv[ni]  = scemb[sid * D_ + n];
        b0v[ni] = bremb[0 * D_ + n];
        b1v[ni] = bremb[1 * D_ + n];
    }

    const size_t MIDOFF = (size_t)B_ * S_ * D_;
    float colsum[4] = {0.f, 0.f, 0.f, 0.f};

#pragma unroll
    for (int mi = 0; mi < 4; ++mi) {
        const int mrow0 = mt * BM + wm * 64 + mi * 16 + fg * 4;
        float mk[4];
#pragma unroll
        for (int r = 0; r < 4; ++r)
            mk[r] = (mask[(size_t)bb * S_ + mrow0 + r] > 0) ? 1.f : 0.f;
#pragma unroll
        for (int ni = 0; ni < 4; ++ni) {
            const int n = ncolbase + ni * 16 + fr;
#pragma unroll
            for (int r = 0; r < 4; ++r) {
                const float v = acc[mi][ni][r] + bv[ni];
                const float o = v / (1.f + __expf(-v)) + sv[ni];
                const size_t idx = ((size_t)bb * S_ + (size_t)(mrow0 + r)) * D_ + n;
                __builtin_nontemporal_store(o + b0v[ni], &out[idx]);
                __builtin_nontemporal_store(o + b1v[ni], &out[MIDOFF + idx]);
                colsum[ni] += mk[r] * o;
            }
        }
    }

#pragma unroll
    for (int ni = 0; ni < 4; ++ni) {
        float s = colsum[ni];
        s += __shfl_xor(s, 16);
        s += __shfl_xor(s, 32);
        if (fg == 0)
            atomicAdd(&ws[(size_t)bb * D_ + (ncolbase + ni * 16 + fr)], s);
    }
}

__global__ void finalize(const int* __restrict__ mask,
                         const float* __restrict__ ws,
                         const float* __restrict__ bremb,
                         float* __restrict__ out)
{
    const int b = blockIdx.x;
    const int tid = threadIdx.x;

    int c = 0;
    for (int s = tid; s < S_; s += 256)
        c += (mask[(size_t)b * S_ + s] > 0) ? 1 : 0;
#pragma unroll
    for (int m = 1; m < 64; m <<= 1)
        c += __shfl_xor(c, m);

    __shared__ int part[4];
    if ((tid & 63) == 0) part[tid >> 6] = c;
    __syncthreads();
    const float denom = fmaxf((float)(part[0] + part[1] + part[2] + part[3]), 1e-6f);
    const float inv = 1.f / denom;

    const size_t LOWOFF = (size_t)2 * B_ * S_ * D_;
    for (int e = tid; e < D_; e += 256)
        out[LOWOFF + (size_t)b * D_ + e] = ws[(size_t)b * D_ + e] * inv + bremb[2 * D_ + e];
}

extern "C" void kernel_launch(void* const* d_in, const int* in_sizes, int n_in,
                              void* d_out, int out_size, void* d_ws, size_t ws_size,
                              hipStream_t stream) {
    const float* midi     = (const float*)d_in[0];
    const int*   scale_id = (const int*)d_in[1];
    const int*   mask     = (const int*)d_in[2];
    const float* W        = (const float*)d_in[3];
    const float* bias     = (const float*)d_in[4];
    const float* scemb    = (const float*)d_in[5];
    const float* bremb    = (const float*)d_in[6];
    float* out = (float*)d_out;
    float* colws = (float*)d_ws;

    const size_t COLWS_B = (size_t)B_ * D_ * sizeof(float);            // 128 KB
    const size_t WBF_B   = (size_t)3 * D_ * D_ * sizeof(short);        // 6 MB
    const size_t ABF_B   = (size_t)B_ * S_ * D_ * sizeof(short);       // 128 MB
    const size_t need    = COLWS_B + WBF_B + ABF_B;

    hipMemsetAsync(colws, 0, COLWS_B, stream);

    if (ws_size >= need) {
        __hip_bfloat16* wBf = (__hip_bfloat16*)((char*)d_ws + COLWS_B);
        __hip_bfloat16* aBf = (__hip_bfloat16*)((char*)d_ws + COLWS_B + WBF_B);
        cvt_bf16<<<dim3(2048), dim3(256), 0, stream>>>(
            (const float4v*)midi, (bf16x8*)aBf, (B_ * S_ * D_) / 8);
        cvt_bf16<<<dim3(512), dim3(256), 0, stream>>>(
            (const float4v*)W, (bf16x8*)wBf, (3 * D_ * D_) / 8);
        fused_gemm_bf16<<<dim3(B_ * (S_ / BM) * (D_ / BN)), dim3(256), 0, stream>>>(
            aBf, wBf, scale_id, mask, bias, scemb, bremb, out, colws);
    } else {
        fused_gemm_f32<<<dim3(B_ * (S_ / BM) * (D_ / BN)), dim3(256), 0, stream>>>(
            midi, scale_id, mask, W, bias, scemb, bremb, out, colws);
    }

    finalize<<<dim3(B_), dim3(256), 0, stream>>>(mask, colws, bremb, out);
}

// Round 8
// 345.454 us; speedup vs baseline: 1.1734x; 1.1734x over previous
//
#include <hip/hip_runtime.h>
#include <hip/hip_bf16.h>

#define B_ 32
#define S_ 2048
#define D_ 1024

// 256x128 tile, BK=32, 8 waves (4Mx2N, 64x64 each), triple-buffered 72KB LDS
#define BM 256
#define BN 128
#define BK 32
#define NKT (D_ / BK)   // 32 K-tiles

typedef __attribute__((ext_vector_type(8))) short bf16x8;
typedef __attribute__((ext_vector_type(4))) float f32x4;
typedef __attribute__((ext_vector_type(4))) float float4v;

#define AS1 __attribute__((address_space(1)))
#define AS3 __attribute__((address_space(3)))

// f32 -> bf16 round-to-nearest-even on raw bits
__device__ __forceinline__ short f2bf(float f) {
    union { float f; unsigned u; } uf;
    uf.f = f;
    unsigned u = uf.u;
    u += 0x7FFFu + ((u >> 16) & 1u);
    return (short)(u >> 16);
}

// ---------------- pre-convert: f32 -> bf16, 8 floats/thread ----------------
__global__ __launch_bounds__(256) void cvt_bf16(const float4v* __restrict__ src,
                                                bf16x8* __restrict__ dst, int n8) {
    const int stride = gridDim.x * blockDim.x;
    for (int i = blockIdx.x * blockDim.x + threadIdx.x; i < n8; i += stride) {
        float4v a = src[2 * i], b = src[2 * i + 1];
        bf16x8 v;
#pragma unroll
        for (int j = 0; j < 4; ++j) {
            v[j]     = f2bf(a[j]);
            v[4 + j] = f2bf(b[j]);
        }
        dst[i] = v;
    }
}

// ============================================================================
// LDS swizzle (64B rows, BK=32): stored byte = (r*64 + c) ^ ((r&7)<<4).
// Read pattern (16 fr-lanes x 4 fg-slots) -> 64 distinct 16B slots = 2 lanes
// per slot = conflict-free. Staging: linear LDS dest (tid*16) + inverse-mapped
// global source (r,s recovered from LDS-offset bits).
// Pipeline: triple buffer; per K-tile: vmcnt(3); barrier; stage t+2 (3 gll);
// 16 MFMA. Cover = 2 K-tiles. Zero garbage staging.
// ============================================================================

// ---- stage tile kt into buffer SB: A rows 0-127, A rows 128-255, B (3 gll) --
#define STAGE(SB, kt) do {                                                     \
    const __hip_bfloat16* _ga0 = aBase + (size_t)srow * D_ + (kt) * BK + scol; \
    __builtin_amdgcn_global_load_lds((const AS1 unsigned int*)_ga0,            \
        (AS3 unsigned int*)((char*)&As[SB][0] + tid * 16), 16, 0, 0);          \
    const __hip_bfloat16* _ga1 = aBase + (size_t)(srow + 128) * D_ + (kt) * BK + scol; \
    __builtin_amdgcn_global_load_lds((const AS1 unsigned int*)_ga1,            \
        (AS3 unsigned int*)((char*)&As[SB][0] + 8192 + tid * 16), 16, 0, 0);   \
    const __hip_bfloat16* _gb = bBase + (size_t)srow * D_ + (kt) * BK + scol;  \
    __builtin_amdgcn_global_load_lds((const AS1 unsigned int*)_gb,             \
        (AS3 unsigned int*)((char*)&Bs[SB][0] + tid * 16), 16, 0, 0);          \
} while (0)

// ---- compute one K-tile from buffer CB: 8 ds_read_b128, 16 MFMA ----
#define COMPUTE(CB) do {                                                       \
    bf16x8 _af[4], _bv[4];                                                     \
    _Pragma("unroll")                                                          \
    for (int _mi = 0; _mi < 4; ++_mi)                                          \
        _af[_mi] = *(const bf16x8*)((const char*)&As[CB][0] + aRd + _mi * 1024); \
    _Pragma("unroll")                                                          \
    for (int _ni = 0; _ni < 4; ++_ni)                                          \
        _bv[_ni] = *(const bf16x8*)((const char*)&Bs[CB][0] + bRd + _ni * 1024); \
    __builtin_amdgcn_s_setprio(1);                                             \
    _Pragma("unroll")                                                          \
    for (int _mi = 0; _mi < 4; ++_mi)                                          \
        _Pragma("unroll")                                                      \
        for (int _ni = 0; _ni < 4; ++_ni)                                      \
            acc[_mi][_ni] = __builtin_amdgcn_mfma_f32_16x16x32_bf16(           \
                _af[_mi], _bv[_ni], acc[_mi][_ni], 0, 0, 0);                   \
    __builtin_amdgcn_s_setprio(0); } while (0)

#define VMW(n)  asm volatile("s_waitcnt vmcnt(" #n ")" ::: "memory")
#define SBAR()  asm volatile("s_barrier" ::: "memory")

// one K-tile: wait own 3 groups of tile t; barrier; stage t+2; compute t
#define KITER(CB, SB, ktn) do { VMW(3); SBAR(); STAGE(SB, ktn); COMPUTE(CB); } while (0)

__global__ __launch_bounds__(512, 4) void fused_gemm_bf16(
    const __hip_bfloat16* __restrict__ aBf,   // [B][S][D] bf16 (pre-converted)
    const __hip_bfloat16* __restrict__ wBf,   // [3][D][D] bf16 (pre-converted)
    const int*   __restrict__ scale_id,
    const int*   __restrict__ mask,
    const float* __restrict__ bias,
    const float* __restrict__ scemb,
    const float* __restrict__ bremb,
    float*       __restrict__ out,
    float*       __restrict__ colws)
{
    __shared__ __align__(16) short As[3][BM * BK];   // 3 x 16 KB
    __shared__ __align__(16) short Bs[3][BN * BK];   // 3 x  8 KB  (72 KB total)

    const int tid = threadIdx.x;
    const int lane = tid & 63;
    const int wid = tid >> 6;                  // 0..7
    const int wm = wid >> 1, wn = wid & 1;     // 4x2 waves, 64x64 each

    // chunked XCD swizzle (NWG = 2048, divisible by 8)
    const int NTI = D_ / BN;  // 8
    const int MTI = S_ / BM;  // 8
    const int NWG = B_ * MTI * NTI;
    const int CPX = NWG / 8;
    int lid = ((int)blockIdx.x % 8) * CPX + ((int)blockIdx.x / 8);
    int nt = lid % NTI;
    int mt = (lid / NTI) % MTI;
    int bb = lid / (NTI * MTI);

    const int sid = scale_id[bb];
    const __hip_bfloat16* aBase = aBf + ((size_t)bb * S_ + (size_t)mt * BM) * D_;
    const __hip_bfloat16* bBase = wBf + ((size_t)sid * D_ + (size_t)nt * BN) * D_;

    // staging inverse map: thread's LDS dest = tid*16 (linear); recover the
    // logical (row, slot) whose swizzled address equals it.
    // L bits (within 512B group): r2=b8, r1=b7, r0=b6^b8, s1=b5^b7, s0=b4^b6^b8
    const int l5 = tid & 31;                           // 16B-chunk idx in 512B
    const int ir0 = ((l5 >> 2) ^ (l5 >> 4)) & 1;
    const int ir1 = (l5 >> 3) & 1;
    const int ir2 = (l5 >> 4) & 1;
    const int is1 = ((l5 >> 1) ^ (l5 >> 3)) & 1;
    const int is0 = (l5 ^ (l5 >> 2) ^ (l5 >> 4)) & 1;
    const int srow = (tid >> 5) * 8 + ir2 * 4 + ir1 * 2 + ir0;   // 0..127
    const int scol = (is1 * 2 + is0) * 8;                        // bf16 col

    // read-side swizzled base addrs (row&7 == fr&7, uniform per lane)
    const int fr = lane & 15;
    const int fg = lane >> 4;
    const int aRd = (((wm * 64 + fr) * 64) + fg * 16) ^ ((fr & 7) << 4);
    const int bRd = (((wn * 64 + fr) * 64) + fg * 16) ^ ((fr & 7) << 4);

    f32x4 acc[4][4];
#pragma unroll
    for (int mi = 0; mi < 4; ++mi)
#pragma unroll
        for (int ni = 0; ni < 4; ++ni)
            acc[mi][ni] = (f32x4){0.f, 0.f, 0.f, 0.f};

    // prologue: tiles 0,1 into buffers 0,1
    STAGE(0, 0);
    STAGE(1, 1);

#pragma unroll 1
    for (int t = 0; t < NKT - 2; t += 3) {
        KITER(0, 2, t + 2);
        KITER(1, 0, t + 3);
        KITER(2, 1, t + 4);
    }
    // tiles 30, 31: no staging, drain
    VMW(3); SBAR(); COMPUTE(0);
    VMW(0); SBAR(); COMPUTE(1);

    __syncthreads();   // lgkm drain; LDS reusable

    // ---- epilogue phase 1: silu + scale_embed in-register, masked colsums ----
    // acc[mi][ni]: row = wm*64 + mi*16 + fg*4 + r;  col = wn*64 + ni*16 + fr
    const int colb = nt * BN;
    float bv[4], sv[4];
#pragma unroll
    for (int ni = 0; ni < 4; ++ni) {
        const int n = colb + wn * 64 + ni * 16 + fr;
        bv[ni] = bias[sid * D_ + n];
        sv[ni] = scemb[sid * D_ + n];
    }

    float colsum[4] = {0.f, 0.f, 0.f, 0.f};
#pragma unroll
    for (int mi = 0; mi < 4; ++mi) {
        const int mrow0 = mt * BM + wm * 64 + mi * 16 + fg * 4;
        float mk[4];
#pragma unroll
        for (int r = 0; r < 4; ++r)
            mk[r] = (mask[(size_t)bb * S_ + mrow0 + r] > 0) ? 1.f : 0.f;
#pragma unroll
        for (int ni = 0; ni < 4; ++ni)
#pragma unroll
            for (int r = 0; r < 4; ++r) {
                const float v = acc[mi][ni][r] + bv[ni];
                const float o = v / (1.f + __expf(-v)) + sv[ni];  // silu + scale_embed
                acc[mi][ni][r] = o;
                colsum[ni] += mk[r] * o;
            }
    }

#pragma unroll
    for (int ni = 0; ni < 4; ++ni) {
        float s = colsum[ni];
        s += __shfl_xor(s, 16);
        s += __shfl_xor(s, 32);
        if (fg == 0) {
            const int n = colb + wn * 64 + ni * 16 + fr;
            atomicAdd(&colws[(size_t)bb * D_ + n], s);
        }
    }

    // ---- epilogue phase 2: LDS bounce -> 128B-contiguous float4 stores ----
    // ldsF[64][132] f32 = 33.8 KB (fits in As' 48 KB). Per mi round: 64-row
    // x 128-col slab; stores in 4 col-quarters, 8 lanes x 16B = 128B lines.
    float* ldsF = (float*)&As[0][0];
    const int lr = tid >> 3;      // 0..63 read row
    const int c8 = tid & 7;       // col-quad within quarter

    float4v b0q[4], b1q[4];
#pragma unroll
    for (int q = 0; q < 4; ++q) {
        const int gcol = colb + q * 32 + c8 * 4;
        b0q[q] = *(const float4v*)&bremb[0 * D_ + gcol];
        b1q[q] = *(const float4v*)&bremb[1 * D_ + gcol];
    }

    const size_t MIDOFF = (size_t)B_ * S_ * D_;

#pragma unroll
    for (int mi = 0; mi < 4; ++mi) {
#pragma unroll
        for (int ni = 0; ni < 4; ++ni)
#pragma unroll
            for (int r = 0; r < 4; ++r)
                ldsF[(wm * 16 + fg * 4 + r) * 132 + wn * 64 + ni * 16 + fr] =
                    acc[mi][ni][r];
        __syncthreads();

        const int grow = mt * BM + (lr >> 4) * 64 + mi * 16 + (lr & 15);
        const size_t rowbase = ((size_t)bb * S_ + grow) * D_ + colb;
#pragma unroll
        for (int q = 0; q < 4; ++q) {
            float4v v = *(const float4v*)&ldsF[lr * 132 + q * 32 + c8 * 4];
            __builtin_nontemporal_store(v + b0q[q], (float4v*)&out[rowbase + q * 32 + c8 * 4]);
            __builtin_nontemporal_store(v + b1q[q], (float4v*)&out[MIDOFF + rowbase + q * 32 + c8 * 4]);
        }
        __syncthreads();
    }
}

// ---------------- fallback path (f32 reg-staging, 128^2, 2-barrier) --------
#define FBM 128
#define FBN 128
#define FBK 64
#define FNK (D_ / FBK)

__global__ __launch_bounds__(256, 2) void fused_gemm_f32(
    const float* __restrict__ midi,
    const int*   __restrict__ scale_id,
    const int*   __restrict__ mask,
    const float* __restrict__ W,
    const float* __restrict__ bias,
    const float* __restrict__ scemb,
    const float* __restrict__ bremb,
    float*       __restrict__ out,
    float*       __restrict__ ws)
{
    __shared__ __align__(16) short Asf[FBM * FBK];
    __shared__ __align__(16) short Bsf[FBM * FBK];

    const int tid = threadIdx.x;
    const int NTI = D_ / FBN;
    const int MTI = S_ / FBM;
    const int NWG = B_ * MTI * NTI;
    const int CPX = NWG / 8;
    int lid = ((int)blockIdx.x % 8) * CPX + ((int)blockIdx.x / 8);
    int nt = lid % NTI;
    int mt = (lid / NTI) % MTI;
    int bb = lid / (NTI * MTI);

    const int sid = scale_id[bb];
    const float* aBase = midi + ((size_t)bb * S_ + (size_t)mt * FBM) * D_;
    const float* bBase = W + ((size_t)sid * D_ + (size_t)nt * FBN) * D_;

    const int r0 = tid >> 3;
    const int kp = (tid & 7) * 8;

    float4v aL[4], aH[4], bL[4], bH[4];

    auto load_regs = [&](int kt) {
        const int kc = kt * FBK + kp;
#pragma unroll
        for (int i = 0; i < 4; ++i) {
            const float* pa = aBase + (size_t)(r0 + 32 * i) * D_ + kc;
            aL[i] = *(const float4v*)pa;
            aH[i] = *(const float4v*)(pa + 4);
            const float* pb = bBase + (size_t)(r0 + 32 * i) * D_ + kc;
            bL[i] = *(const float4v*)pb;
            bH[i] = *(const float4v*)(pb + 4);
        }
    };

    auto write_lds = [&]() {
#pragma unroll
        for (int i = 0; i < 4; ++i) {
            const int row = r0 + 32 * i;
            const int off = (row * FBK + kp) ^ ((row & 7) << 3);
            bf16x8 va, vb;
#pragma unroll
            for (int j = 0; j < 4; ++j) {
                va[j]     = f2bf(aL[i][j]);
                va[4 + j] = f2bf(aH[i][j]);
                vb[j]     = f2bf(bL[i][j]);
                vb[4 + j] = f2bf(bH[i][j]);
            }
            *(bf16x8*)&Asf[off] = va;
            *(bf16x8*)&Bsf[off] = vb;
        }
    };

    f32x4 acc[4][4];
#pragma unroll
    for (int mi = 0; mi < 4; ++mi)
#pragma unroll
        for (int ni = 0; ni < 4; ++ni)
            acc[mi][ni] = (f32x4){0.f, 0.f, 0.f, 0.f};

    const int lane = tid & 63;
    const int wid = tid >> 6;
    const int wm = wid >> 1, wn = wid & 1;
    const int fr = lane & 15;
    const int fg = lane >> 4;

    load_regs(0);
    write_lds();
    __syncthreads();

    for (int kt = 0; kt < FNK; ++kt) {
        if (kt + 1 < FNK) load_regs(kt + 1);
#pragma unroll
        for (int kk = 0; kk < 2; ++kk) {
            bf16x8 af[4], bfr[4];
#pragma unroll
            for (int mi = 0; mi < 4; ++mi) {
                const int row = wm * 64 + mi * 16 + fr;
                const int off = (row * FBK + kk * 32 + fg * 8) ^ ((row & 7) << 3);
                af[mi] = *(const bf16x8*)&Asf[off];
            }
#pragma unroll
            for (int ni = 0; ni < 4; ++ni) {
                const int row = wn * 64 + ni * 16 + fr;
                const int off = (row * FBK + kk * 32 + fg * 8) ^ ((row & 7) << 3);
                bfr[ni] = *(const bf16x8*)&Bsf[off];
            }
#pragma unroll
            for (int mi = 0; mi < 4; ++mi)
#pragma unroll
                for (int ni = 0; ni < 4; ++ni)
                    acc[mi][ni] = __builtin_amdgcn_mfma_f32_16x16x32_bf16(
                        af[mi], bfr[ni], acc[mi][ni], 0, 0, 0);
        }
        __syncthreads();
        if (kt + 1 < FNK) write_lds();
        __syncthreads();
    }

    const int ncolbase = nt * FBN + wn * 64;
    float bv[4], sv[4], b0v[4], b1v[4];
#pragma unroll
    for (int ni = 0; ni < 4; ++ni) {
        const int n = ncolbase + ni * 16 + fr;
        bv[ni]  = bias[sid * D_ + n];
        sv[ni]  = scemb[sid * D_ + n];
        b0v[ni] = bremb[0 * D_ + n];
        b1v[ni] = bremb[1 * D_ + n];
    }

    const size_t MIDOFF = (size_t)B_ * S_ * D_;
    float colsum[4] = {0.f, 0.f, 0.f, 0.f};

#pragma unroll
    for (int mi = 0; mi < 4; ++mi) {
        const int mrow0 = mt * FBM + wm * 64 + mi * 16 + fg * 4;
        float mk[4];
#pragma unroll
        for (int r = 0; r < 4; ++r)
            mk[r] = (mask[(size_t)bb * S_ + mrow0 + r] > 0) ? 1.f : 0.f;
#pragma unroll
        for (int ni = 0; ni < 4; ++ni) {
            const int n = ncolbase + ni * 16 + fr;
#pragma unroll
            for (int r = 0; r < 4; ++r) {
                const float v = acc[mi][ni][r] + bv[ni];
                const float o = v / (1.f + __expf(-v)) + sv[ni];
                const size_t idx = ((size_t)bb * S_ + (size_t)(mrow0 + r)) * D_ + n;
                __builtin_nontemporal_store(o + b0v[ni], &out[idx]);
                __builtin_nontemporal_store(o + b1v[ni], &out[MIDOFF + idx]);
                colsum[ni] += mk[r] * o;
            }
        }
    }

#pragma unroll
    for (int ni = 0; ni < 4; ++ni) {
        float s = colsum[ni];
        s += __shfl_xor(s, 16);
        s += __shfl_xor(s, 32);
        if (fg == 0)
            atomicAdd(&ws[(size_t)bb * D_ + (ncolbase + ni * 16 + fr)], s);
    }
}

__global__ void finalize(const int* __restrict__ mask,
                         const float* __restrict__ ws,
                         const float* __restrict__ bremb,
                         float* __restrict__ out)
{
    const int b = blockIdx.x;
    const int tid = threadIdx.x;

    int c = 0;
    for (int s = tid; s < S_; s += 256)
        c += (mask[(size_t)b * S_ + s] > 0) ? 1 : 0;
#pragma unroll
    for (int m = 1; m < 64; m <<= 1)
        c += __shfl_xor(c, m);

    __shared__ int part[4];
    if ((tid & 63) == 0) part[tid >> 6] = c;
    __syncthreads();
    const float denom = fmaxf((float)(part[0] + part[1] + part[2] + part[3]), 1e-6f);
    const float inv = 1.f / denom;

    const size_t LOWOFF = (size_t)2 * B_ * S_ * D_;
    for (int e = tid; e < D_; e += 256)
        out[LOWOFF + (size_t)b * D_ + e] = ws[(size_t)b * D_ + e] * inv + bremb[2 * D_ + e];
}

extern "C" void kernel_launch(void* const* d_in, const int* in_sizes, int n_in,
                              void* d_out, int out_size, void* d_ws, size_t ws_size,
                              hipStream_t stream) {
    const float* midi     = (const float*)d_in[0];
    const int*   scale_id = (const int*)d_in[1];
    const int*   mask     = (const int*)d_in[2];
    const float* W        = (const float*)d_in[3];
    const float* bias     = (const float*)d_in[4];
    const float* scemb    = (const float*)d_in[5];
    const float* bremb    = (const float*)d_in[6];
    float* out = (float*)d_out;
    float* colws = (float*)d_ws;

    const size_t COLWS_B = (size_t)B_ * D_ * sizeof(float);            // 128 KB
    const size_t WBF_B   = (size_t)3 * D_ * D_ * sizeof(short);        // 6 MB
    const size_t ABF_B   = (size_t)B_ * S_ * D_ * sizeof(short);       // 128 MB
    const size_t need    = COLWS_B + WBF_B + ABF_B;

    hipMemsetAsync(colws, 0, COLWS_B, stream);

    if (ws_size >= need) {
        __hip_bfloat16* wBf = (__hip_bfloat16*)((char*)d_ws + COLWS_B);
        __hip_bfloat16* aBf = (__hip_bfloat16*)((char*)d_ws + COLWS_B + WBF_B);
        cvt_bf16<<<dim3(2048), dim3(256), 0, stream>>>(
            (const float4v*)midi, (bf16x8*)aBf, (B_ * S_ * D_) / 8);
        cvt_bf16<<<dim3(512), dim3(256), 0, stream>>>(
            (const float4v*)W, (bf16x8*)wBf, (3 * D_ * D_) / 8);
        fused_gemm_bf16<<<dim3(B_ * (S_ / BM) * (D_ / BN)), dim3(512), 0, stream>>>(
            aBf, wBf, scale_id, mask, bias, scemb, bremb, out, colws);
    } else {
        fused_gemm_f32<<<dim3(B_ * (S_ / FBM) * (D_ / FBN)), dim3(256), 0, stream>>>(
            midi, scale_id, mask, W, bias, scemb, bremb, out, colws);
    }

    finalize<<<dim3(B_), dim3(256), 0, stream>>>(mask, colws, bremb, out);
}